// Round 6
// baseline (267.624 us; speedup 1.0000x reference)
//
#include <hip/hip_runtime.h>
#include <stdint.h>

// Problem constants (match reference file)
#define B_ 8
#define C_ 256
#define N_ 16384
#define K_ 128

#define CT 32                    // channels per block tile
#define PT 1024                  // points per block
#define SUB 64                   // points per staged sub-tile
#define NSUB (PT / SUB)          // 16
#define XBLKS (N_ / PT)          // 16
#define YBLKS (C_ / CT)          // 8
#define ACC_ENTRIES (CT * K_)    // 4096
#define NBLOCKS (XBLKS * YBLKS * B_)                      // 1024
#define WS_BYTES ((size_t)NBLOCKS * ACC_ENTRIES * 4u)     // 16 MiB of partials

// Monotone float->uint key: preserves order under unsigned max.
// Every finite float maps to key > 0, so key==0 is the "empty" sentinel.
__device__ __forceinline__ unsigned f2key(float f) {
    unsigned u = __float_as_uint(f);
    return (u & 0x80000000u) ? ~u : (u | 0x80000000u);
}
__device__ __forceinline__ float key2f(unsigned k) {
    unsigned u = (k & 0x80000000u) ? (k & 0x7fffffffu) : ~k;
    return __uint_as_float(u);
}

// LDS: tile 2*32*65*4 = 16640 B (dbuf, pad 65 -> 2-way banks on write AND
// transpose read, free per m136) + acc 32*129*4 = 16512 B (pad 129 ->
// atomic banks (ch+cc)%32, spreads collisions) = 33.2 KB
// -> 4 blocks/CU, 16 waves/CU.
__global__ __launch_bounds__(256, 4) void seghead_fused(
    const float* __restrict__ pf,     // [B][C][N]
    const int* __restrict__ cid,      // [B][N], -1..K-1
    float* __restrict__ out1,         // [B*N][C] transposed features
    unsigned* __restrict__ pws,       // [NBLOCKS][4096] partial keys, or nullptr
    unsigned* __restrict__ gacc)      // atomic fallback (pre-zeroed) when pws==nullptr
{
    __shared__ float tile[2][CT][SUB + 1];
    __shared__ unsigned acc[CT][K_ + 1];

    const int t  = threadIdx.x;
    const int xb = blockIdx.x, yb = blockIdx.y, b = blockIdx.z;
    const int c0 = yb * CT;
    const int n0 = xb * PT;

    for (int i = t; i < CT * (K_ + 1); i += 256) ((unsigned*)acc)[i] = 0u;

    // ---- load-phase mapping: thread owns channels {cy, cy+16}, points x4*4..+3
    const int x4 = t & 15;
    const int cy = t >> 4;
    const float* src0 = pf + ((size_t)(b * C_ + c0 + cy) * N_) + n0 + x4 * 4;
    const int*   csrc = cid + (size_t)b * N_ + n0 + x4 * 4;

    auto gload = [&](int r, int s) -> float4 {
        return *(const float4*)(src0 + (size_t)r * 16 * N_ + s * SUB);
    };
    auto cload = [&](int s) -> int4 {
        return *(const int4*)(csrc + s * SUB);
    };
    // stage sub-tile into LDS buf + fold into segment-max acc (from registers)
    auto stage = [&](int nb, float4 v0, float4 v1, int4 cc) {
        float* row0 = &tile[nb][cy][x4 * 4];
        float* row1 = &tile[nb][16 + cy][x4 * 4];
        row0[0] = v0.x; row0[1] = v0.y; row0[2] = v0.z; row0[3] = v0.w;
        row1[0] = v1.x; row1[1] = v1.y; row1[2] = v1.z; row1[3] = v1.w;
        if (cc.x >= 0) { atomicMax(&acc[cy][cc.x], f2key(v0.x)); atomicMax(&acc[16 + cy][cc.x], f2key(v1.x)); }
        if (cc.y >= 0) { atomicMax(&acc[cy][cc.y], f2key(v0.y)); atomicMax(&acc[16 + cy][cc.y], f2key(v1.y)); }
        if (cc.z >= 0) { atomicMax(&acc[cy][cc.z], f2key(v0.z)); atomicMax(&acc[16 + cy][cc.z], f2key(v1.z)); }
        if (cc.w >= 0) { atomicMax(&acc[cy][cc.w], f2key(v0.w)); atomicMax(&acc[16 + cy][cc.w], f2key(v1.w)); }
    };

    // ---- process-phase mapping: lane = 8 pts x 8 ch-groups; float4 stores
    const int lane = t & 63;
    const int w    = t >> 6;
    const int g4   = (lane & 7) * 4;   // channel group base (0..28)
    const int pp   = lane >> 3;        // 0..7
    auto process = [&](int nb, int s) {
        #pragma unroll
        for (int it = 0; it < 2; ++it) {
            const int p = w * 16 + it * 8 + pp;
            float4 o;
            o.x = tile[nb][g4 + 0][p];
            o.y = tile[nb][g4 + 1][p];
            o.z = tile[nb][g4 + 2][p];
            o.w = tile[nb][g4 + 3][p];
            *(float4*)&out1[((size_t)b * N_ + n0 + s * SUB + p) * C_ + c0 + g4] = o;
        }
    };

    // prologue: stage sub-tile 0
    {
        float4 v0 = gload(0, 0), v1 = gload(1, 0);
        int4 cc = cload(0);
        stage(0, v0, v1, cc);
    }
    __syncthreads();

    // main loop: prefetch s+1 (global->regs) BEFORE processing s; single
    // barrier per sub-tile. vmcnt wait for the prefetch lands after the
    // transpose reads/stores have issued.
    int nb = 0;
    for (int s = 0; s < NSUB; ++s) {
        float4 v0, v1; int4 cc;
        const bool more = (s + 1 < NSUB);
        if (more) { v0 = gload(0, s + 1); v1 = gload(1, s + 1); cc = cload(s + 1); }
        process(nb, s);
        if (more) stage(nb ^ 1, v0, v1, cc);
        __syncthreads();
        nb ^= 1;
    }

    // ---- flush block-local maxima ----
    const int blin = (b * YBLKS + yb) * XBLKS + xb;
    if (pws) {
        unsigned* dst = pws + (size_t)blin * ACC_ENTRIES;
        for (int i = t; i < ACC_ENTRIES; i += 256)
            dst[i] = acc[i >> 7][i & 127];          // non-atomic, coalesced
    } else {
        for (int i = t; i < ACC_ENTRIES; i += 256) {
            const unsigned k = acc[i >> 7][i & 127];
            if (k) atomicMax(&gacc[((size_t)b * K_ + (i & 127)) * C_ + c0 + (i >> 7)], k);
        }
    }
}

// ws mode: reduce 16 x-partials per output element, decode keys -> floats.
// Thread mapping puts cl (stride-1 in pws) fastest so the 16 MiB of partial
// reads are fully coalesced; the 1 MiB of strided out0 writes ride on L2.
__global__ void seghead_reduce_ws(const unsigned* __restrict__ pws,
                                  float* __restrict__ out0) {
    const int tid  = blockIdx.x * 256 + threadIdx.x;
    const int cl   = tid & 127;        // cluster (fastest in pws)
    const int rest = tid >> 7;
    const int c    = rest & 255;       // channel
    const int b    = rest >> 8;
    const unsigned* p = pws + (size_t)(b * YBLKS + (c >> 5)) * XBLKS * ACC_ENTRIES
                            + (c & 31) * K_ + cl;
    unsigned m = 0;
    #pragma unroll
    for (int x = 0; x < XBLKS; ++x) m = max(m, p[(size_t)x * ACC_ENTRIES]);
    out0[((size_t)b * K_ + cl) * C_ + c] = m ? key2f(m) : 0.0f;
}

// atomic-fallback mode: decode keys in place
__global__ void seghead_decode(unsigned* __restrict__ gacc) {
    const int i = blockIdx.x * 256 + threadIdx.x;
    const unsigned k = gacc[i];
    ((float*)gacc)[i] = k ? key2f(k) : 0.0f;
}

extern "C" void kernel_launch(void* const* d_in, const int* in_sizes, int n_in,
                              void* d_out, int out_size, void* d_ws, size_t ws_size,
                              hipStream_t stream) {
    const float* pf   = (const float*)d_in[0];
    const int*   cidp = (const int*)d_in[1];

    float* out0 = (float*)d_out;
    float* out1 = out0 + (size_t)B_ * K_ * C_;

    dim3 grid(XBLKS, YBLKS, B_);
    if (ws_size >= WS_BYTES) {
        unsigned* pws = (unsigned*)d_ws;
        seghead_fused<<<grid, 256, 0, stream>>>(pf, cidp, out1, pws, nullptr);
        seghead_reduce_ws<<<(B_ * K_ * C_) / 256, 256, 0, stream>>>(pws, out0);
    } else {
        hipMemsetAsync(d_out, 0, (size_t)B_ * K_ * C_ * 4, stream);
        seghead_fused<<<grid, 256, 0, stream>>>(pf, cidp, out1, nullptr, (unsigned*)d_out);
        seghead_decode<<<(B_ * K_ * C_) / 256, 256, 0, stream>>>((unsigned*)d_out);
    }
}